// Round 1
// baseline (905.961 us; speedup 1.0000x reference)
//
#include <hip/hip_runtime.h>

// KAN Jacobi layer: y[b,o,s] = sum_{i,d} P_d(tanh(x[b,i,s])) * C[i,o,d]
// B=4, I=64, S=65536, O=128, degree=4 (D=5), alpha=beta=1.
//
// Jacobi recurrence with a=b=1:
//   P0 = 1
//   P1 = 2x
//   P2 = 1.875*x*P1 - 0.75
//   P3 = (56/30)*x*P2 - 0.8*P1
//   P4 = 1.875*x*P3 - (5/6)*P2
//
// Structure: 1 thread = 1 sample (b,s). tanh computed once into LDS
// (64 f32/thread = 64 KB/block, conflict-free: t[i][tid]).
// 4 passes over o-chunks of 32 accumulators; coeffs are wave-uniform
// (loop-counter indexed) -> scalar loads, inner loop is v_fmac with
// SGPR coeff operand. ~41k FMA/thread -> compute-bound ~150us expected.

#define BB 4
#define II 64
#define SS 65536
#define OO 128
#define OC 32
#define TPB 256

__global__ __launch_bounds__(TPB)
void kan_jacobi_kernel(const float* __restrict__ x,
                       const float* __restrict__ coeffs,
                       float* __restrict__ y) {
    __shared__ float t_lds[II][TPB];  // 64 KB

    const int tid = threadIdx.x;
    const int s   = blockIdx.x * TPB + tid;
    const int b   = blockIdx.y;

    // ---- load x column, tanh once, stage in LDS ----
    const float* xb = x + (size_t)b * II * SS + s;
    #pragma unroll
    for (int i = 0; i < II; ++i) {
        t_lds[i][tid] = tanhf(xb[(size_t)i * SS]);
    }
    __syncthreads();

    const float A2 = 1.875f,              C2 = -0.75f;
    const float A3 = 1.8666666666666667f, C3 = -0.8f;
    const float A4 = 1.875f,              C4 = -0.8333333333333334f;

    // ---- 4 passes over output chunks of 32 ----
    for (int oc = 0; oc < OO; oc += OC) {
        float acc[OC];
        #pragma unroll
        for (int o = 0; o < OC; ++o) acc[o] = 0.0f;

        for (int i = 0; i < II; ++i) {
            const float t  = t_lds[i][tid];
            const float p1 = 2.0f * t;
            const float p2 = fmaf(A2 * t, p1, C2);
            float p3 = A3 * t * p2;  p3 = fmaf(C3, p1, p3);
            float p4 = A4 * t * p3;  p4 = fmaf(C4, p2, p4);

            const float* c = coeffs + ((size_t)i * OO + oc) * 5;
            #pragma unroll
            for (int o = 0; o < OC; ++o) {
                float a = acc[o];
                a += c[o * 5 + 0];
                a = fmaf(c[o * 5 + 1], p1, a);
                a = fmaf(c[o * 5 + 2], p2, a);
                a = fmaf(c[o * 5 + 3], p3, a);
                a = fmaf(c[o * 5 + 4], p4, a);
                acc[o] = a;
            }
        }

        float* yp = y + ((size_t)b * OO + oc) * SS + s;
        #pragma unroll
        for (int o = 0; o < OC; ++o) {
            yp[(size_t)o * SS] = acc[o];
        }
    }
}

extern "C" void kernel_launch(void* const* d_in, const int* in_sizes, int n_in,
                              void* d_out, int out_size, void* d_ws, size_t ws_size,
                              hipStream_t stream) {
    const float* x      = (const float*)d_in[0];
    const float* coeffs = (const float*)d_in[1];
    float* y            = (float*)d_out;

    dim3 grid(SS / TPB, BB);   // 256 x 4 = 1024 blocks
    dim3 block(TPB);
    kan_jacobi_kernel<<<grid, block, 0, stream>>>(x, coeffs, y);
}

// Round 2
// 272.291 us; speedup vs baseline: 3.3272x; 3.3272x over previous
//
#include <hip/hip_runtime.h>
#include <hip/hip_bf16.h>

// KAN Jacobi layer as bf16 MFMA GEMM:
//   y[b,o,s] = bias[o] + sum_{k=(d-1)*64+i, d=1..4} C2[o,k] * P_d(tanh(x[b,i,s]))
//   bias[o]  = sum_i coeffs[i][o][0]   (P0 == 1)
// B=4, I=64, S=65536, O=128. K'=256. HBM floor ~31us (192 MiB @ 6.3 TB/s).
//
// kernel 1a: coeffs f32 (i,o,d) -> swizzled bf16 table cws[o][k'] (64 KB)
//            byte addr = (o*512 + k'*2) ^ ((o&7)<<4)   (bank-balanced b128 reads)
// kernel 1b: bias[o] reduction
// kernel 2:  512 blocks x 256 thr (4 waves). Stage cws -> LDS (global_load_lds x16B).
//            Wave covers o=128 x s=32 (2 sub-strips of 16). B-frags (Jacobi) are
//            built IN REGISTERS: lane l computes polys for s = s0+(l&15),
//            i = i0 + 8*(l>>4) + j  == exact mfma_f32_16x16x32_bf16 B layout.
//            A-frags: ds_read_b128 from swizzled LDS. Acc init = bias.

#define II 64
#define SS 65536
#define OO 128

typedef __attribute__((ext_vector_type(8))) short short8;
typedef __attribute__((ext_vector_type(4))) float f32x4;

// ---------------- kernel 1a: coeffs -> swizzled bf16 table ----------------
__global__ __launch_bounds__(256)
void kan_prep_coeffs(const float* __restrict__ coeffs, ushort* __restrict__ cws) {
    int n = blockIdx.x * 256 + threadIdx.x;      // 40960 = 64*128*5
    int i = n / 640;
    int rem = n - i * 640;
    int o = rem / 5;
    int d = rem - o * 5;
    if (d == 0) return;                           // degree 0 -> bias kernel
    int kp = (d - 1) * 64 + i;                    // k' in [0,256)
    int byte = (o * 512 + kp * 2) ^ ((o & 7) << 4);
    __hip_bfloat16 h = __float2bfloat16(coeffs[n]);
    cws[byte >> 1] = *reinterpret_cast<ushort*>(&h);
}

// ---------------- kernel 1b: bias[o] = sum_i coeffs[i][o][0] ----------------
__global__ __launch_bounds__(128)
void kan_prep_bias(const float* __restrict__ coeffs, float* __restrict__ bias) {
    int o = threadIdx.x;
    float s = 0.f;
    #pragma unroll
    for (int i = 0; i < 64; ++i) s += coeffs[i * 640 + o * 5];
    bias[o] = s;
}

// ---------------- main MFMA kernel ----------------
__device__ __forceinline__ float fast_tanh(float v) {
    // tanh(v) = 1 - 2/(exp2(2*log2e*v)+1); large |v| saturates correctly.
    float e = exp2f(v * 2.885390082f);
    float r = __builtin_amdgcn_rcpf(e + 1.0f);
    return fmaf(-2.0f, r, 1.0f);
}

__device__ __forceinline__ short8 pack8(const float* p) {
    union { short8 v; uint u[4]; } r;
    #pragma unroll
    for (int q = 0; q < 4; ++q) {
        __hip_bfloat162 h = __float22bfloat162_rn(make_float2(p[2*q], p[2*q+1]));
        r.u[q] = *reinterpret_cast<uint*>(&h);
    }
    return r.v;
}

__global__ __launch_bounds__(256, 2)
void kan_mfma(const float* __restrict__ x, const ushort* __restrict__ cws,
              const float* __restrict__ bias, float* __restrict__ y) {
    __shared__ __align__(16) ushort clds[32768];   // 64 KB swizzled C2 table

    const int tid  = threadIdx.x;
    const int w    = tid >> 6;        // wave 0..3
    const int l    = tid & 63;
    const int g    = l >> 4;          // k-chunk group 0..3
    const int l15  = l & 15;
    const int b    = blockIdx.y;
    const int sgrp = blockIdx.x;      // 0..127 -> 512 samples each

    // ---- stage C table: 64 KB = 16 iters x 256 thr x 16 B (linear) ----
    const char* gsrc  = (const char*)cws;
    char*       lbase = (char*)clds;
    #pragma unroll
    for (int q = 0; q < 16; ++q) {
        int off = (q * 256 + tid) * 16;
        __builtin_amdgcn_global_load_lds(
            (const __attribute__((address_space(1))) uint*)(gsrc + off),
            (__attribute__((address_space(3))) uint*)(lbase + off),
            16, 0, 0);
    }

    // ---- per-lane bias fragments (match C/D layout: o = of*16 + g*4 + r) ----
    f32x4 bias4[8];
    #pragma unroll
    for (int of = 0; of < 8; ++of)
        bias4[of] = *(const f32x4*)(bias + of * 16 + g * 4);

    __syncthreads();   // drains global_load_lds (vmcnt) per barrier semantics

    const int swz = (l15 & 7) << 4;

    for (int st = 0; st < 4; ++st) {
        const int s0 = sgrp * 512 + st * 128 + w * 32 + l15;

        f32x4 acc[8][2];
        #pragma unroll
        for (int of = 0; of < 8; ++of) { acc[of][0] = bias4[of]; acc[of][1] = bias4[of]; }

        #pragma unroll
        for (int half = 0; half < 2; ++half) {
            const int i0 = half * 32;

            // ---- load 16 x values (lane: 8 i's x 2 s-substrips) ----
            float xv[2][8];
            #pragma unroll
            for (int sf = 0; sf < 2; ++sf) {
                const float* xp = x + (size_t)(b * II + i0 + g * 8) * SS + s0 + 16 * sf;
                #pragma unroll
                for (int j = 0; j < 8; ++j) xv[sf][j] = xp[(size_t)j * SS];
            }

            // ---- tanh + Jacobi(1,1) recurrence + bf16 pack -> B-fragments ----
            short8 bf[2][4];
            #pragma unroll
            for (int sf = 0; sf < 2; ++sf) {
                float p1a[8], p2a[8], p3a[8], p4a[8];
                #pragma unroll
                for (int j = 0; j < 8; ++j) {
                    float t  = fast_tanh(xv[sf][j]);
                    float p1 = t + t;                                  // P1 = 2x
                    float p2 = fmaf(1.875f * t, p1, -0.75f);           // P2
                    float p3 = fmaf(1.8666666666666667f * t, p2, -0.8f * p1);
                    float p4 = fmaf(1.875f * t, p3, -0.8333333333333333f * p2);
                    p1a[j] = p1; p2a[j] = p2; p3a[j] = p3; p4a[j] = p4;
                }
                bf[sf][0] = pack8(p1a); bf[sf][1] = pack8(p2a);
                bf[sf][2] = pack8(p3a); bf[sf][3] = pack8(p4a);
            }

            // ---- MFMA sweep: A from LDS (reused across 2 s-substrips) ----
            #pragma unroll
            for (int d = 0; d < 4; ++d) {
                const int kbyte = d * 128 + i0 * 2 + g * 16;
                #pragma unroll
                for (int of = 0; of < 8; ++of) {
                    const int o    = of * 16 + l15;
                    const int boff = (o * 512 + kbyte) ^ swz;
                    short8 a = *(const short8*)(lbase + boff);
                    acc[of][0] = __builtin_amdgcn_mfma_f32_16x16x32_bf16(a, bf[0][d], acc[of][0], 0, 0, 0);
                    acc[of][1] = __builtin_amdgcn_mfma_f32_16x16x32_bf16(a, bf[1][d], acc[of][1], 0, 0, 0);
                }
            }
        }

        // ---- store: D layout col=l&15 (s), row=g*4+r (o) ----
        #pragma unroll
        for (int of = 0; of < 8; ++of) {
            float* yp = y + (size_t)(b * OO + of * 16 + g * 4) * SS + s0;
            #pragma unroll
            for (int r = 0; r < 4; ++r) {
                yp[(size_t)r * SS]      = acc[of][0][r];
                yp[(size_t)r * SS + 16] = acc[of][1][r];
            }
        }
    }
}

extern "C" void kernel_launch(void* const* d_in, const int* in_sizes, int n_in,
                              void* d_out, int out_size, void* d_ws, size_t ws_size,
                              hipStream_t stream) {
    const float* x      = (const float*)d_in[0];
    const float* coeffs = (const float*)d_in[1];
    float* y            = (float*)d_out;

    ushort* cws  = (ushort*)d_ws;                        // 64 KB bf16 table
    float*  bias = (float*)((char*)d_ws + 65536);        // 512 B

    kan_prep_coeffs<<<dim3(160), dim3(256), 0, stream>>>(coeffs, cws);
    kan_prep_bias  <<<dim3(1),   dim3(128), 0, stream>>>(coeffs, bias);
    kan_mfma       <<<dim3(128, 4), dim3(256), 0, stream>>>(x, cws, bias, y);
}

// Round 3
// 202.611 us; speedup vs baseline: 4.4714x; 1.3439x over previous
//
#include <hip/hip_runtime.h>
#include <hip/hip_bf16.h>

// KAN Jacobi layer as bf16 MFMA GEMM (32x32x16 for full-line coalescing):
//   y[b,o,s] = bias[o] + sum_{k'=(d-1)*64+i, d=1..4} C2[o,k'] * P_d(tanh(x[b,i,s]))
//   bias[o]  = sum_i coeffs[i][o][0]   (P0 == 1)
// B=4, I=64, S=65536, O=128, K'=256. HBM floor ~31us (192 MiB @ 6.3 TB/s).
//
// Structure: 512 blocks x 256 thr (4 waves, 2 blocks/CU exactly).
//   - 64 KB swizzled bf16 C2 table staged to LDS once per block.
//   - Each wave owns a 32-s strip x all 128 o (4 o-tile accumulators f32x16).
//   - B-frags (Jacobi polys) built in registers: lane l = s-column l&31,
//     k = 8*(l>>5)+j  == mfma_f32_32x32x16_bf16 operand layout. x-loads and
//     y-stores are 128 B contiguous per 32-lane half -> full cache lines.
//   - A-frags: ds_read_b128 from XOR-swizzled LDS (4-way = b128 floor).
//   - x software-pipelined one s-tile ahead; bias re-loaded per tile (L1-hot).

#define II 64
#define SS 65536
#define OO 128

typedef __attribute__((ext_vector_type(8))) short short8;
typedef __attribute__((ext_vector_type(4))) float f32x4;
typedef __attribute__((ext_vector_type(16))) float f32x16;

// ---------------- kernel 1a: coeffs -> swizzled bf16 table ----------------
__global__ __launch_bounds__(256)
void kan_prep_coeffs(const float* __restrict__ coeffs, ushort* __restrict__ cws) {
    int n = blockIdx.x * 256 + threadIdx.x;      // 40960 = 64*128*5 exactly
    int i = n / 640;
    int rem = n - i * 640;
    int o = rem / 5;
    int d = rem - o * 5;
    if (d == 0) return;                           // degree 0 -> bias kernel
    int kp = (d - 1) * 64 + i;                    // k' in [0,256)
    int byte = (o * 512 + kp * 2) ^ ((o & 7) << 4);
    __hip_bfloat16 h = __float2bfloat16(coeffs[n]);
    cws[byte >> 1] = *reinterpret_cast<ushort*>(&h);
}

// ---------------- kernel 1b: bias[o] = sum_i coeffs[i][o][0] ----------------
__global__ __launch_bounds__(128)
void kan_prep_bias(const float* __restrict__ coeffs, float* __restrict__ bias) {
    int o = threadIdx.x;
    float s = 0.f;
    #pragma unroll
    for (int i = 0; i < 64; ++i) s += coeffs[i * 640 + o * 5];
    bias[o] = s;
}

// ---------------- main MFMA kernel ----------------
__device__ __forceinline__ float fast_tanh(float v) {
    float e = exp2f(v * 2.885390082f);
    float r = __builtin_amdgcn_rcpf(e + 1.0f);
    return fmaf(-2.0f, r, 1.0f);
}

__device__ __forceinline__ short8 pack8(const float* p) {
    union { short8 v; uint u[4]; } r;
    #pragma unroll
    for (int q = 0; q < 4; ++q) {
        __hip_bfloat162 h = __float22bfloat162_rn(make_float2(p[2*q], p[2*q+1]));
        r.u[q] = *reinterpret_cast<uint*>(&h);
    }
    return r.v;
}

__global__ __launch_bounds__(256)
void kan_mfma(const float* __restrict__ x, const ushort* __restrict__ cws,
              const float* __restrict__ bias, float* __restrict__ y) {
    __shared__ __align__(16) ushort clds[32768];   // 64 KB swizzled C2 table

    const int tid  = threadIdx.x;
    const int w    = tid >> 6;        // wave 0..3
    const int l    = tid & 63;
    const int lh   = l >> 5;          // k-half (0: k 0-7, 1: k 8-15)
    const int ls   = l & 31;          // s-column / o-row within tile
    const int b    = blockIdx.y;
    const int sgrp = blockIdx.x;      // 0..127 -> 512 samples per block

    // ---- stage C table: 64 KB = 16 iters x 256 thr x 16 B (linear) ----
    const char* gsrc  = (const char*)cws;
    char*       lbase = (char*)clds;
    #pragma unroll
    for (int q = 0; q < 16; ++q) {
        int off = (q * 256 + tid) * 16;
        __builtin_amdgcn_global_load_lds(
            (const __attribute__((address_space(1))) uint*)(gsrc + off),
            (__attribute__((address_space(3))) uint*)(lbase + off),
            16, 0, 0);
    }
    __syncthreads();

    const int sbase = sgrp * 512 + w * 128;
    const float* xb = x + (size_t)b * II * SS;
    const int swz = (ls & 7) << 4;

    // x buffers, ping-pong (st fully unrolled -> static indexing)
    float xbuf[2][4][8];

    // prologue: load s-tile 0 (each load: 32 lanes x 4B contiguous = 128 B/row)
    #pragma unroll
    for (int ig = 0; ig < 4; ++ig) {
        const float* xp = xb + (size_t)(ig * 16 + 8 * lh) * SS + sbase + ls;
        #pragma unroll
        for (int j = 0; j < 8; ++j) xbuf[0][ig][j] = xp[(size_t)j * SS];
    }

    #pragma unroll
    for (int st = 0; st < 4; ++st) {
        const int cur = st & 1;
        const int s0  = sbase + st * 32;

        // ---- prefetch next s-tile's x under this tile's compute ----
        if (st < 3) {
            #pragma unroll
            for (int ig = 0; ig < 4; ++ig) {
                const float* xp = xb + (size_t)(ig * 16 + 8 * lh) * SS + sbase + (st + 1) * 32 + ls;
                #pragma unroll
                for (int j = 0; j < 8; ++j) xbuf[cur ^ 1][ig][j] = xp[(size_t)j * SS];
            }
        }

        // ---- acc init = bias fragments (L1-hot after first tile) ----
        f32x16 acc[4];
        #pragma unroll
        for (int ot = 0; ot < 4; ++ot) {
            #pragma unroll
            for (int q = 0; q < 4; ++q) {
                f32x4 bv = *(const f32x4*)(bias + ot * 32 + q * 8 + 4 * lh);
                #pragma unroll
                for (int r = 0; r < 4; ++r) acc[ot][q * 4 + r] = bv[r];
            }
        }

        // ---- per i-group: tanh + Jacobi + pack, then 16 MFMA ----
        #pragma unroll
        for (int ig = 0; ig < 4; ++ig) {
            float p1a[8], p2a[8], p3a[8], p4a[8];
            #pragma unroll
            for (int j = 0; j < 8; ++j) {
                float t  = fast_tanh(xbuf[cur][ig][j]);
                float p1 = t + t;                                   // P1 = 2x
                float p2 = fmaf(1.875f * t, p1, -0.75f);            // P2
                float p3 = fmaf(1.8666666666666667f * t, p2, -0.8f * p1);
                float p4 = fmaf(1.875f * t, p3, -0.8333333333333333f * p2);
                p1a[j] = p1; p2a[j] = p2; p3a[j] = p3; p4a[j] = p4;
            }
            short8 bf[4];
            bf[0] = pack8(p1a); bf[1] = pack8(p2a);
            bf[2] = pack8(p3a); bf[3] = pack8(p4a);

            #pragma unroll
            for (int di = 0; di < 4; ++di) {
                const int kt = di * 4 + ig;               // k-window
                #pragma unroll
                for (int ot = 0; ot < 4; ++ot) {
                    const int o    = ot * 32 + ls;
                    const int boff = (o * 512 + kt * 32 + 16 * lh) ^ swz;
                    short8 a = *(const short8*)(lbase + boff);
                    acc[ot] = __builtin_amdgcn_mfma_f32_32x32x16_bf16(a, bf[di], acc[ot], 0, 0, 0);
                }
            }
        }

        // ---- store: D col = l&31 (s), row = (r&3)+8*(r>>2)+4*(l>>5) (o) ----
        // per store instr: 2 x 32 lanes x 4 B = 2 full 128 B lines
        #pragma unroll
        for (int ot = 0; ot < 4; ++ot) {
            #pragma unroll
            for (int q = 0; q < 4; ++q) {
                #pragma unroll
                for (int rr = 0; rr < 4; ++rr) {
                    const int orow = ot * 32 + rr + 8 * q + 4 * lh;
                    y[(size_t)(b * OO + orow) * SS + s0 + ls] = acc[ot][q * 4 + rr];
                }
            }
        }
    }
}

extern "C" void kernel_launch(void* const* d_in, const int* in_sizes, int n_in,
                              void* d_out, int out_size, void* d_ws, size_t ws_size,
                              hipStream_t stream) {
    const float* x      = (const float*)d_in[0];
    const float* coeffs = (const float*)d_in[1];
    float* y            = (float*)d_out;

    ushort* cws  = (ushort*)d_ws;                        // 64 KB bf16 table
    float*  bias = (float*)((char*)d_ws + 65536);        // 512 B

    kan_prep_coeffs<<<dim3(160), dim3(256), 0, stream>>>(coeffs, cws);
    kan_prep_bias  <<<dim3(1),   dim3(128), 0, stream>>>(coeffs, bias);
    kan_mfma       <<<dim3(128, 4), dim3(256), 0, stream>>>(x, cws, bias, y);
}